// Round 4
// baseline (686.716 us; speedup 1.0000x reference)
//
#include <hip/hip_runtime.h>

// ---------------------------------------------------------------------------
// GCN: out = (relu(conv2(relu(conv1(x@We+be)))))@Wo + bo
// conv(h) = pull_sum(norm * (h@W)[src] over CSR row dst) + b
// CSR built by dst, self-loop as first entry of each row; norm precomputed.
// ---------------------------------------------------------------------------

#define WS_ALIGN(x) (((x) + 255) & ~(size_t)255)

// flag=1 => edge_index is int64, flag=0 => int32
__global__ void detect_i64_kernel(const unsigned* __restrict__ p, int* __restrict__ flag) {
    __shared__ int any;
    if (threadIdx.x == 0) any = 0;
    __syncthreads();
    int nz = 0;
    for (int i = threadIdx.x; i < 2048; i += blockDim.x)
        nz |= (p[2 * i + 1] != 0u) ? 1 : 0;
    if (nz) atomicOr(&any, 1);
    __syncthreads();
    if (threadIdx.x == 0) *flag = (any == 0) ? 1 : 0;
}

__global__ void init_deg_kernel(unsigned* __restrict__ deg, int n) {
    int i = blockIdx.x * blockDim.x + threadIdx.x;
    if (i < n) deg[i] = 1u;  // self-loop
}

__global__ void count_deg_kernel(const void* __restrict__ ep, const int* __restrict__ flag,
                                 unsigned* __restrict__ deg, int E) {
    int i = blockIdx.x * blockDim.x + threadIdx.x;
    if (i >= E) return;
    int d = (*flag) ? (int)((const long long*)ep)[(size_t)E + i]
                    : ((const int*)ep)[(size_t)E + i];
    atomicAdd(&deg[d], 1u);
}

// Single-block inclusive-scan -> row_ptr (exclusive form: row_ptr[0]=0, [i+1]=incl[i])
__global__ __launch_bounds__(1024) void scan_kernel(const unsigned* __restrict__ deg,
                                                    int* __restrict__ row_ptr, int n) {
    __shared__ int lds[1024];
    __shared__ int carry;
    const int tid = threadIdx.x;
    if (tid == 0) { carry = 0; row_ptr[0] = 0; }
    __syncthreads();
    for (int base = 0; base < n; base += 1024) {
        int i = base + tid;
        int v = (i < n) ? (int)deg[i] : 0;
        lds[tid] = v;
        __syncthreads();
        for (int off = 1; off < 1024; off <<= 1) {
            int add = (tid >= off) ? lds[tid - off] : 0;
            __syncthreads();
            lds[tid] += add;
            __syncthreads();
        }
        if (i < n) row_ptr[i + 1] = carry + lds[tid];
        __syncthreads();
        if (tid == 0) carry += lds[1023];
        __syncthreads();
    }
}

__global__ void finalize_dinv_kernel(float* __restrict__ dinv, int n) {
    int i = blockIdx.x * blockDim.x + threadIdx.x;
    if (i < n) {
        unsigned d = ((const unsigned*)dinv)[i];
        dinv[i] = rsqrtf((float)d);
    }
}

// self-loop at row start; init fill past it
__global__ void selfloop_fill_kernel(const int* __restrict__ row_ptr,
                                     const float* __restrict__ dinv,
                                     int* __restrict__ fill, int* __restrict__ col,
                                     float* __restrict__ nrm, int n) {
    int i = blockIdx.x * blockDim.x + threadIdx.x;
    if (i >= n) return;
    int pos = row_ptr[i];
    col[pos] = i;
    float di = dinv[i];
    nrm[pos] = di * di;
    fill[i] = pos + 1;
}

__global__ void edge_fill_kernel(const void* __restrict__ ep, const int* __restrict__ flag,
                                 const float* __restrict__ dinv, int* __restrict__ fill,
                                 int* __restrict__ col, float* __restrict__ nrm, int E) {
    int i = blockIdx.x * blockDim.x + threadIdx.x;
    if (i >= E) return;
    int s, d;
    if (*flag) {
        const long long* p = (const long long*)ep;
        s = (int)p[i];
        d = (int)p[(size_t)E + i];
    } else {
        const int* p = (const int*)ep;
        s = p[i];
        d = p[(size_t)E + i];
    }
    int pos = atomicAdd(&fill[d], 1);
    col[pos] = s;
    nrm[pos] = dinv[s] * dinv[d];
}

// out[i][:] = bias[:] + sum_j nrm[j] * t[col[j]][:]  over CSR row i. Wave per node.
__global__ __launch_bounds__(256) void agg_pull_kernel(
    const int* __restrict__ row_ptr, const int* __restrict__ col,
    const float* __restrict__ nrm, const float* __restrict__ t,
    const float* __restrict__ bias, float* __restrict__ out, int n) {
    int node = blockIdx.x * 4 + (threadIdx.x >> 6);
    int lane = threadIdx.x & 63;
    if (node >= n) return;
    int j0 = row_ptr[node], j1 = row_ptr[node + 1];
    float2 acc = ((const float2*)bias)[lane];
    int j = j0;
    for (; j + 1 < j1; j += 2) {
        int c0 = col[j], c1 = col[j + 1];
        float w0 = nrm[j], w1 = nrm[j + 1];
        float2 v0 = ((const float2*)(t + (size_t)c0 * 128))[lane];
        float2 v1 = ((const float2*)(t + (size_t)c1 * 128))[lane];
        acc.x = fmaf(v0.x, w0, acc.x);
        acc.y = fmaf(v0.y, w0, acc.y);
        acc.x = fmaf(v1.x, w1, acc.x);
        acc.y = fmaf(v1.y, w1, acc.y);
    }
    if (j < j1) {
        int c = col[j];
        float w = nrm[j];
        float2 v = ((const float2*)(t + (size_t)c * 128))[lane];
        acc.x = fmaf(v.x, w, acc.x);
        acc.y = fmaf(v.y, w, acc.y);
    }
    ((float2*)(out + (size_t)node * 128))[lane] = acc;
}

// C[n,ncol] = (relu_in? relu(A) : A)[n,128] @ W[128,ncol] (+ bias)
// 64x64 tile per block, 256 threads, 4x4 micro-tile per thread.
__global__ __launch_bounds__(256) void gemm_k128_kernel(
    const float* __restrict__ A, const float* __restrict__ W,
    const float* __restrict__ bias, float* __restrict__ C,
    int n, int ncol, int relu_in) {
    __shared__ float Alds[64 * 128];  // 32 KB
    __shared__ float Wlds[128 * 64];  // 32 KB
    const int row0 = blockIdx.x * 64;
    const int col0 = blockIdx.y * 64;

    for (int i = threadIdx.x; i < 128 * 64; i += 256) {
        int k = i >> 6, c = i & 63;
        Wlds[i] = W[k * ncol + col0 + c];
    }
    {
        const float4* A4 = (const float4*)A;
        float4* L4 = (float4*)Alds;
        for (int i = threadIdx.x; i < 64 * 32; i += 256) {
            int r = row0 + (i >> 5);
            float4 v = make_float4(0.f, 0.f, 0.f, 0.f);
            if (r < n) v = A4[(size_t)r * 32 + (i & 31)];
            if (relu_in) {
                v.x = fmaxf(v.x, 0.f); v.y = fmaxf(v.y, 0.f);
                v.z = fmaxf(v.z, 0.f); v.w = fmaxf(v.w, 0.f);
            }
            L4[i] = v;
        }
    }
    __syncthreads();

    const int cg = threadIdx.x & 15;
    const int rg = threadIdx.x >> 4;
    float acc[4][4] = {};

#define ACC_ROW(I, AV)                                  \
    acc[I][0] = fmaf(AV.x, w0.x, acc[I][0]);            \
    acc[I][1] = fmaf(AV.x, w0.y, acc[I][1]);            \
    acc[I][2] = fmaf(AV.x, w0.z, acc[I][2]);            \
    acc[I][3] = fmaf(AV.x, w0.w, acc[I][3]);            \
    acc[I][0] = fmaf(AV.y, w1.x, acc[I][0]);            \
    acc[I][1] = fmaf(AV.y, w1.y, acc[I][1]);            \
    acc[I][2] = fmaf(AV.y, w1.z, acc[I][2]);            \
    acc[I][3] = fmaf(AV.y, w1.w, acc[I][3]);            \
    acc[I][0] = fmaf(AV.z, w2.x, acc[I][0]);            \
    acc[I][1] = fmaf(AV.z, w2.y, acc[I][1]);            \
    acc[I][2] = fmaf(AV.z, w2.z, acc[I][2]);            \
    acc[I][3] = fmaf(AV.z, w2.w, acc[I][3]);            \
    acc[I][0] = fmaf(AV.w, w3.x, acc[I][0]);            \
    acc[I][1] = fmaf(AV.w, w3.y, acc[I][1]);            \
    acc[I][2] = fmaf(AV.w, w3.z, acc[I][2]);            \
    acc[I][3] = fmaf(AV.w, w3.w, acc[I][3]);

#pragma unroll 4
    for (int k4 = 0; k4 < 32; ++k4) {
        int k = k4 * 4;
        float4 a0 = *(const float4*)&Alds[(rg * 4 + 0) * 128 + k];
        float4 a1 = *(const float4*)&Alds[(rg * 4 + 1) * 128 + k];
        float4 a2 = *(const float4*)&Alds[(rg * 4 + 2) * 128 + k];
        float4 a3 = *(const float4*)&Alds[(rg * 4 + 3) * 128 + k];
        float4 w0 = *(const float4*)&Wlds[(k + 0) * 64 + cg * 4];
        float4 w1 = *(const float4*)&Wlds[(k + 1) * 64 + cg * 4];
        float4 w2 = *(const float4*)&Wlds[(k + 2) * 64 + cg * 4];
        float4 w3 = *(const float4*)&Wlds[(k + 3) * 64 + cg * 4];
        ACC_ROW(0, a0)
        ACC_ROW(1, a1)
        ACC_ROW(2, a2)
        ACC_ROW(3, a3)
    }
#undef ACC_ROW

    float4 b4 = make_float4(0.f, 0.f, 0.f, 0.f);
    if (bias) b4 = *(const float4*)&bias[col0 + cg * 4];
#pragma unroll
    for (int i = 0; i < 4; ++i) {
        int r = row0 + rg * 4 + i;
        if (r < n) {
            float4 o;
            o.x = acc[i][0] + b4.x;
            o.y = acc[i][1] + b4.y;
            o.z = acc[i][2] + b4.z;
            o.w = acc[i][3] + b4.w;
            *(float4*)&C[(size_t)r * ncol + col0 + cg * 4] = o;
        }
    }
}

extern "C" void kernel_launch(void* const* d_in, const int* in_sizes, int n_in,
                              void* d_out, int out_size, void* d_ws, size_t ws_size,
                              hipStream_t stream) {
    const float* x  = (const float*)d_in[0];
    const void*  ei = d_in[1];
    const float* We = (const float*)d_in[2];
    const float* be = (const float*)d_in[3];
    const float* W1 = (const float*)d_in[4];
    const float* b1 = (const float*)d_in[5];
    const float* W2 = (const float*)d_in[6];
    const float* b2 = (const float*)d_in[7];
    const float* Wo = (const float*)d_in[8];
    const float* bo = (const float*)d_in[9];
    const int N = in_sizes[0] / 128;
    const int E = in_sizes[1] / 2;
    const int M = E + N;  // CSR entries incl. self-loops

    char* ws = (char*)d_ws;
    size_t off = 0;
    int*   flag = (int*)(ws + off);   off += 256;
    float* dinv = (float*)(ws + off); off += WS_ALIGN((size_t)N * 4);        // deg then dinv
    int*   rowp = (int*)(ws + off);   off += WS_ALIGN((size_t)(N + 1) * 4);
    int*   fill = (int*)(ws + off);   off += WS_ALIGN((size_t)N * 4);
    int*   colw = (int*)(ws + off);   off += WS_ALIGN((size_t)M * 4);
    float* nrmw = (float*)(ws + off); off += WS_ALIGN((size_t)M * 4);
    float* bufA = (float*)(ws + off); off += WS_ALIGN((size_t)N * 128 * 4);
    float* bufB = (float*)(ws + off); off += WS_ALIGN((size_t)N * 128 * 4);

    const int nb_n = (N + 255) / 256;
    const int nb_e = (E + 255) / 256;

    // CSR build + normalization
    detect_i64_kernel<<<1, 256, 0, stream>>>((const unsigned*)ei, flag);
    init_deg_kernel<<<nb_n, 256, 0, stream>>>((unsigned*)dinv, N);
    count_deg_kernel<<<nb_e, 256, 0, stream>>>(ei, flag, (unsigned*)dinv, E);
    scan_kernel<<<1, 1024, 0, stream>>>((const unsigned*)dinv, rowp, N);
    finalize_dinv_kernel<<<nb_n, 256, 0, stream>>>(dinv, N);
    selfloop_fill_kernel<<<nb_n, 256, 0, stream>>>(rowp, dinv, fill, colw, nrmw, N);
    edge_fill_kernel<<<nb_e, 256, 0, stream>>>(ei, flag, dinv, fill, colw, nrmw, E);

    dim3 blk(256);
    dim3 g128((N + 63) / 64, 2);
    dim3 g64((N + 63) / 64, 1);
    const int agg_blocks = (N + 3) / 4;

    // encoder: h0 = x@We + be -> bufA
    gemm_k128_kernel<<<g128, blk, 0, stream>>>(x, We, be, bufA, N, 128, 0);
    // conv1: t1 = h0@W1 -> bufB ; out1 = Agg(t1)+b1 -> bufA
    gemm_k128_kernel<<<g128, blk, 0, stream>>>(bufA, W1, nullptr, bufB, N, 128, 0);
    agg_pull_kernel<<<agg_blocks, blk, 0, stream>>>(rowp, colw, nrmw, bufB, b1, bufA, N);
    // conv2: t2 = relu(out1)@W2 -> bufB ; out2 = Agg(t2)+b2 -> bufA
    gemm_k128_kernel<<<g128, blk, 0, stream>>>(bufA, W2, nullptr, bufB, N, 128, 1);
    agg_pull_kernel<<<agg_blocks, blk, 0, stream>>>(rowp, colw, nrmw, bufB, b2, bufA, N);
    // decoder: out = relu(out2)@Wo + bo -> d_out
    gemm_k128_kernel<<<g64, blk, 0, stream>>>(bufA, Wo, bo, (float*)d_out, N, 64, 1);
}

// Round 5
// 647.402 us; speedup vs baseline: 1.0607x; 1.0607x over previous
//
#include <hip/hip_runtime.h>

// ---------------------------------------------------------------------------
// GCN: out = (relu(conv2(relu(conv1(x@We+be)))))@Wo + bo
// conv(h): t = h@W;  out[i] = b + dinv[i]*( dinv[i]*t[i] + sum_{(s->i)} dinv[s]*t[s] )
// CSR (edges only, by dst) built per call: count -> scan -> atomic fill (col only).
// ---------------------------------------------------------------------------

#define WS_ALIGN(x) (((x) + 255) & ~(size_t)255)

// flag=1 => edge_index is int64, flag=0 => int32
__global__ void detect_i64_kernel(const unsigned* __restrict__ p, int* __restrict__ flag) {
    __shared__ int any;
    if (threadIdx.x == 0) any = 0;
    __syncthreads();
    int nz = 0;
    for (int i = threadIdx.x; i < 2048; i += blockDim.x)
        nz |= (p[2 * i + 1] != 0u) ? 1 : 0;
    if (nz) atomicOr(&any, 1);
    __syncthreads();
    if (threadIdx.x == 0) *flag = (any == 0) ? 1 : 0;
}

__global__ void zero_u32_kernel(unsigned* __restrict__ a, int n) {
    int i = blockIdx.x * blockDim.x + threadIdx.x;
    if (i < n) a[i] = 0u;
}

__global__ void count_deg_kernel(const void* __restrict__ ep, const int* __restrict__ flag,
                                 unsigned* __restrict__ ecnt, int E) {
    int i = blockIdx.x * blockDim.x + threadIdx.x;
    if (i >= E) return;
    int d = (*flag) ? (int)((const long long*)ep)[(size_t)E + i]
                    : ((const int*)ep)[(size_t)E + i];
    atomicAdd(&ecnt[d], 1u);
}

// 3-phase single-block exclusive scan: row_ptr[0]=0, row_ptr[i+1]=sum_{k<=i} ecnt[k]
__global__ __launch_bounds__(1024) void scan_kernel(const unsigned* __restrict__ ecnt,
                                                    int* __restrict__ row_ptr, int n) {
    __shared__ int partial[1024];
    const int tid = threadIdx.x;
    const int chunk = (n + 1023) / 1024;
    const int i0 = tid * chunk;
    const int i1 = min(i0 + chunk, n);
    int s = 0;
    for (int i = i0; i < i1; ++i) s += (int)ecnt[i];
    partial[tid] = s;
    __syncthreads();
    for (int off = 1; off < 1024; off <<= 1) {
        int add = (tid >= off) ? partial[tid - off] : 0;
        __syncthreads();
        partial[tid] += add;
        __syncthreads();
    }
    int run = (tid > 0) ? partial[tid - 1] : 0;
    for (int i = i0; i < i1; ++i) {
        run += (int)ecnt[i];
        row_ptr[i + 1] = run;
    }
    if (tid == 0) row_ptr[0] = 0;
}

// dinv[i] = rsqrt(1 + indegree); fill[i] = row start
__global__ void finalize_kernel(const unsigned* __restrict__ ecnt, const int* __restrict__ rowp,
                                float* __restrict__ dinv, int* __restrict__ fill, int n) {
    int i = blockIdx.x * blockDim.x + threadIdx.x;
    if (i < n) {
        dinv[i] = rsqrtf((float)(ecnt[i] + 1u));
        fill[i] = rowp[i];
    }
}

__global__ void edge_fill_kernel(const void* __restrict__ ep, const int* __restrict__ flag,
                                 int* __restrict__ fill, int* __restrict__ col, int E) {
    int i = blockIdx.x * blockDim.x + threadIdx.x;
    if (i >= E) return;
    int s, d;
    if (*flag) {
        const long long* p = (const long long*)ep;
        s = (int)p[i];
        d = (int)p[(size_t)E + i];
    } else {
        const int* p = (const int*)ep;
        s = p[i];
        d = p[(size_t)E + i];
    }
    int pos = atomicAdd(&fill[d], 1);
    col[pos] = s;
}

// out[i][:] = bias + dinv[i]*( dinv[i]*t[i][:] + sum_j dinv[col[j]]*t[col[j]][:] )
// 32 lanes (float4) per node, 8 nodes per 256-block.
__global__ __launch_bounds__(256) void agg_pull_kernel(
    const int* __restrict__ rowp, const int* __restrict__ col,
    const float* __restrict__ dinv, const float* __restrict__ t,
    const float* __restrict__ bias, float* __restrict__ out, int n) {
    int node = blockIdx.x * 8 + (threadIdx.x >> 5);
    int lane = threadIdx.x & 31;
    if (node >= n) return;
    const float4* T4 = (const float4*)t;
    int j0 = rowp[node], j1 = rowp[node + 1];
    float dn = dinv[node];

    // self-loop: dn * t[node]
    float4 sv = T4[(size_t)node * 32 + lane];
    float4 acc;
    acc.x = sv.x * dn; acc.y = sv.y * dn; acc.z = sv.z * dn; acc.w = sv.w * dn;

    int j = j0;
    for (; j + 3 < j1; j += 4) {
        int c0 = col[j], c1 = col[j + 1], c2 = col[j + 2], c3 = col[j + 3];
        float w0 = dinv[c0], w1 = dinv[c1], w2 = dinv[c2], w3 = dinv[c3];
        float4 v0 = T4[(size_t)c0 * 32 + lane];
        float4 v1 = T4[(size_t)c1 * 32 + lane];
        float4 v2 = T4[(size_t)c2 * 32 + lane];
        float4 v3 = T4[(size_t)c3 * 32 + lane];
        acc.x = fmaf(v0.x, w0, acc.x); acc.y = fmaf(v0.y, w0, acc.y);
        acc.z = fmaf(v0.z, w0, acc.z); acc.w = fmaf(v0.w, w0, acc.w);
        acc.x = fmaf(v1.x, w1, acc.x); acc.y = fmaf(v1.y, w1, acc.y);
        acc.z = fmaf(v1.z, w1, acc.z); acc.w = fmaf(v1.w, w1, acc.w);
        acc.x = fmaf(v2.x, w2, acc.x); acc.y = fmaf(v2.y, w2, acc.y);
        acc.z = fmaf(v2.z, w2, acc.z); acc.w = fmaf(v2.w, w2, acc.w);
        acc.x = fmaf(v3.x, w3, acc.x); acc.y = fmaf(v3.y, w3, acc.y);
        acc.z = fmaf(v3.z, w3, acc.z); acc.w = fmaf(v3.w, w3, acc.w);
    }
    for (; j < j1; ++j) {
        int c = col[j];
        float w = dinv[c];
        float4 v = T4[(size_t)c * 32 + lane];
        acc.x = fmaf(v.x, w, acc.x); acc.y = fmaf(v.y, w, acc.y);
        acc.z = fmaf(v.z, w, acc.z); acc.w = fmaf(v.w, w, acc.w);
    }
    float4 b = ((const float4*)bias)[lane];
    float4 o;
    o.x = fmaf(acc.x, dn, b.x);
    o.y = fmaf(acc.y, dn, b.y);
    o.z = fmaf(acc.z, dn, b.z);
    o.w = fmaf(acc.w, dn, b.w);
    ((float4*)(out + (size_t)node * 128))[lane] = o;
}

// C[n,ncol] = (relu_in? relu(A) : A)[n,128] @ W[128,ncol] (+ bias)
// 64x64 tile per block, 256 threads, 4x4 micro-tile per thread.
__global__ __launch_bounds__(256) void gemm_k128_kernel(
    const float* __restrict__ A, const float* __restrict__ W,
    const float* __restrict__ bias, float* __restrict__ C,
    int n, int ncol, int relu_in) {
    __shared__ float Alds[64 * 128];  // 32 KB
    __shared__ float Wlds[128 * 64];  // 32 KB
    const int row0 = blockIdx.x * 64;
    const int col0 = blockIdx.y * 64;

    for (int i = threadIdx.x; i < 128 * 64; i += 256) {
        int k = i >> 6, c = i & 63;
        Wlds[i] = W[k * ncol + col0 + c];
    }
    {
        const float4* A4 = (const float4*)A;
        float4* L4 = (float4*)Alds;
        for (int i = threadIdx.x; i < 64 * 32; i += 256) {
            int r = row0 + (i >> 5);
            float4 v = make_float4(0.f, 0.f, 0.f, 0.f);
            if (r < n) v = A4[(size_t)r * 32 + (i & 31)];
            if (relu_in) {
                v.x = fmaxf(v.x, 0.f); v.y = fmaxf(v.y, 0.f);
                v.z = fmaxf(v.z, 0.f); v.w = fmaxf(v.w, 0.f);
            }
            L4[i] = v;
        }
    }
    __syncthreads();

    const int cg = threadIdx.x & 15;
    const int rg = threadIdx.x >> 4;
    float acc[4][4] = {};

#define ACC_ROW(I, AV)                                  \
    acc[I][0] = fmaf(AV.x, w0.x, acc[I][0]);            \
    acc[I][1] = fmaf(AV.x, w0.y, acc[I][1]);            \
    acc[I][2] = fmaf(AV.x, w0.z, acc[I][2]);            \
    acc[I][3] = fmaf(AV.x, w0.w, acc[I][3]);            \
    acc[I][0] = fmaf(AV.y, w1.x, acc[I][0]);            \
    acc[I][1] = fmaf(AV.y, w1.y, acc[I][1]);            \
    acc[I][2] = fmaf(AV.y, w1.z, acc[I][2]);            \
    acc[I][3] = fmaf(AV.y, w1.w, acc[I][3]);            \
    acc[I][0] = fmaf(AV.z, w2.x, acc[I][0]);            \
    acc[I][1] = fmaf(AV.z, w2.y, acc[I][1]);            \
    acc[I][2] = fmaf(AV.z, w2.z, acc[I][2]);            \
    acc[I][3] = fmaf(AV.z, w2.w, acc[I][3]);            \
    acc[I][0] = fmaf(AV.w, w3.x, acc[I][0]);            \
    acc[I][1] = fmaf(AV.w, w3.y, acc[I][1]);            \
    acc[I][2] = fmaf(AV.w, w3.z, acc[I][2]);            \
    acc[I][3] = fmaf(AV.w, w3.w, acc[I][3]);

#pragma unroll 4
    for (int k4 = 0; k4 < 32; ++k4) {
        int k = k4 * 4;
        float4 a0 = *(const float4*)&Alds[(rg * 4 + 0) * 128 + k];
        float4 a1 = *(const float4*)&Alds[(rg * 4 + 1) * 128 + k];
        float4 a2 = *(const float4*)&Alds[(rg * 4 + 2) * 128 + k];
        float4 a3 = *(const float4*)&Alds[(rg * 4 + 3) * 128 + k];
        float4 w0 = *(const float4*)&Wlds[(k + 0) * 64 + cg * 4];
        float4 w1 = *(const float4*)&Wlds[(k + 1) * 64 + cg * 4];
        float4 w2 = *(const float4*)&Wlds[(k + 2) * 64 + cg * 4];
        float4 w3 = *(const float4*)&Wlds[(k + 3) * 64 + cg * 4];
        ACC_ROW(0, a0)
        ACC_ROW(1, a1)
        ACC_ROW(2, a2)
        ACC_ROW(3, a3)
    }
#undef ACC_ROW

    float4 b4 = make_float4(0.f, 0.f, 0.f, 0.f);
    if (bias) b4 = *(const float4*)&bias[col0 + cg * 4];
#pragma unroll
    for (int i = 0; i < 4; ++i) {
        int r = row0 + rg * 4 + i;
        if (r < n) {
            float4 o;
            o.x = acc[i][0] + b4.x;
            o.y = acc[i][1] + b4.y;
            o.z = acc[i][2] + b4.z;
            o.w = acc[i][3] + b4.w;
            *(float4*)&C[(size_t)r * ncol + col0 + cg * 4] = o;
        }
    }
}

extern "C" void kernel_launch(void* const* d_in, const int* in_sizes, int n_in,
                              void* d_out, int out_size, void* d_ws, size_t ws_size,
                              hipStream_t stream) {
    const float* x  = (const float*)d_in[0];
    const void*  ei = d_in[1];
    const float* We = (const float*)d_in[2];
    const float* be = (const float*)d_in[3];
    const float* W1 = (const float*)d_in[4];
    const float* b1 = (const float*)d_in[5];
    const float* W2 = (const float*)d_in[6];
    const float* b2 = (const float*)d_in[7];
    const float* Wo = (const float*)d_in[8];
    const float* bo = (const float*)d_in[9];
    const int N = in_sizes[0] / 128;
    const int E = in_sizes[1] / 2;

    char* ws = (char*)d_ws;
    size_t off = 0;
    int*      flag = (int*)(ws + off);      off += 256;
    unsigned* ecnt = (unsigned*)(ws + off); off += WS_ALIGN((size_t)N * 4);
    float*    dinv = (float*)(ws + off);    off += WS_ALIGN((size_t)N * 4);
    int*      rowp = (int*)(ws + off);      off += WS_ALIGN((size_t)(N + 1) * 4);
    int*      fill = (int*)(ws + off);      off += WS_ALIGN((size_t)N * 4);
    int*      colw = (int*)(ws + off);      off += WS_ALIGN((size_t)E * 4);
    float*    bufA = (float*)(ws + off);    off += WS_ALIGN((size_t)N * 128 * 4);
    float*    bufB = (float*)(ws + off);    off += WS_ALIGN((size_t)N * 128 * 4);

    const int nb_n = (N + 255) / 256;
    const int nb_e = (E + 255) / 256;

    // CSR build (edges only) + normalization
    detect_i64_kernel<<<1, 256, 0, stream>>>((const unsigned*)ei, flag);
    zero_u32_kernel<<<nb_n, 256, 0, stream>>>(ecnt, N);
    count_deg_kernel<<<nb_e, 256, 0, stream>>>(ei, flag, ecnt, E);
    scan_kernel<<<1, 1024, 0, stream>>>(ecnt, rowp, N);
    finalize_kernel<<<nb_n, 256, 0, stream>>>(ecnt, rowp, dinv, fill, N);
    edge_fill_kernel<<<nb_e, 256, 0, stream>>>(ei, flag, fill, colw, E);

    dim3 blk(256);
    dim3 g128((N + 63) / 64, 2);
    dim3 g64((N + 63) / 64, 1);
    const int agg_blocks = (N + 7) / 8;

    // encoder: h0 = x@We + be -> bufA
    gemm_k128_kernel<<<g128, blk, 0, stream>>>(x, We, be, bufA, N, 128, 0);
    // conv1: t1 = h0@W1 -> bufB ; out1 = Agg(t1)+b1 -> bufA
    gemm_k128_kernel<<<g128, blk, 0, stream>>>(bufA, W1, nullptr, bufB, N, 128, 0);
    agg_pull_kernel<<<agg_blocks, blk, 0, stream>>>(rowp, colw, dinv, bufB, b1, bufA, N);
    // conv2: t2 = relu(out1)@W2 -> bufB ; out2 = Agg(t2)+b2 -> bufA
    gemm_k128_kernel<<<g128, blk, 0, stream>>>(bufA, W2, nullptr, bufB, N, 128, 1);
    agg_pull_kernel<<<agg_blocks, blk, 0, stream>>>(rowp, colw, dinv, bufB, b2, bufA, N);
    // decoder: out = relu(out2)@Wo + bo -> d_out
    gemm_k128_kernel<<<g64, blk, 0, stream>>>(bufA, Wo, bo, (float*)d_out, N, 64, 1);
}

// Round 6
// 487.903 us; speedup vs baseline: 1.4075x; 1.3269x over previous
//
#include <hip/hip_runtime.h>
#include <hip/hip_fp16.h>

// ---------------------------------------------------------------------------
// GCN: out = (relu(conv2(relu(conv1(x@We+be)))))@Wo + bo
// conv(h): t = h@W (fp16);  out[i] = b + dinv[i]*( dinv[i]*t[i] + sum dinv[s]*t[s] )
// CSR (edges only, by dst): count -> scan -> XCD-partitioned atomic fill.
// ---------------------------------------------------------------------------

#define WS_ALIGN(x) (((x) + 255) & ~(size_t)255)

// flag=1 => edge_index is int64, flag=0 => int32
__global__ void detect_i64_kernel(const unsigned* __restrict__ p, int* __restrict__ flag) {
    __shared__ int any;
    if (threadIdx.x == 0) any = 0;
    __syncthreads();
    int nz = 0;
    for (int i = threadIdx.x; i < 2048; i += blockDim.x)
        nz |= (p[2 * i + 1] != 0u) ? 1 : 0;
    if (nz) atomicOr(&any, 1);
    __syncthreads();
    if (threadIdx.x == 0) *flag = (any == 0) ? 1 : 0;
}

__global__ void zero_u32_kernel(unsigned* __restrict__ a, int n) {
    int i = blockIdx.x * blockDim.x + threadIdx.x;
    if (i < n) a[i] = 0u;
}

__global__ void count_deg_kernel(const void* __restrict__ ep, const int* __restrict__ flag,
                                 unsigned* __restrict__ ecnt, int E) {
    int i = blockIdx.x * blockDim.x + threadIdx.x;
    if (i >= E) return;
    int d = (*flag) ? (int)((const long long*)ep)[(size_t)E + i]
                    : ((const int*)ep)[(size_t)E + i];
    atomicAdd(&ecnt[d], 1u);
}

// 3-phase single-block exclusive scan: row_ptr[0]=0, row_ptr[i+1]=sum_{k<=i} ecnt[k]
__global__ __launch_bounds__(1024) void scan_kernel(const unsigned* __restrict__ ecnt,
                                                    int* __restrict__ row_ptr, int n) {
    __shared__ int partial[1024];
    const int tid = threadIdx.x;
    const int chunk = (n + 1023) / 1024;
    const int i0 = tid * chunk;
    const int i1 = min(i0 + chunk, n);
    int s = 0;
    for (int i = i0; i < i1; ++i) s += (int)ecnt[i];
    partial[tid] = s;
    __syncthreads();
    for (int off = 1; off < 1024; off <<= 1) {
        int add = (tid >= off) ? partial[tid - off] : 0;
        __syncthreads();
        partial[tid] += add;
        __syncthreads();
    }
    int run = (tid > 0) ? partial[tid - 1] : 0;
    for (int i = i0; i < i1 && i0 < n; ++i) {
        run += (int)ecnt[i];
        row_ptr[i + 1] = run;
    }
    if (tid == 0) row_ptr[0] = 0;
}

// dinv[i] = rsqrt(1 + indegree); fill[i] = row start
__global__ void finalize_kernel(const unsigned* __restrict__ ecnt, const int* __restrict__ rowp,
                                float* __restrict__ dinv, int* __restrict__ fill, int n) {
    int i = blockIdx.x * blockDim.x + threadIdx.x;
    if (i < n) {
        dinv[i] = rsqrtf((float)(ecnt[i] + 1u));
        fill[i] = rowp[i];
    }
}

// XCD-partitioned fill: part = bid&7 owns dst range [part*rs, part*rs+rs).
// Round-robin block->XCD dispatch keeps each col range in ONE XCD's L2,
// so scattered 4B writes accumulate in-cache instead of 64B/edge to HBM.
__global__ __launch_bounds__(256) void edge_fill_part_kernel(
    const void* __restrict__ ep, const int* __restrict__ flag,
    int* __restrict__ fill, int* __restrict__ col, int E, int n) {
    int part = blockIdx.x & 7;
    int i = (blockIdx.x >> 3) * 256 + threadIdx.x;
    if (i >= E) return;
    const int rs = (n + 7) >> 3;
    const int lo = part * rs;
    const int hi = min(lo + rs, n);
    int s, d;
    if (*flag) {
        const long long* p = (const long long*)ep;
        d = (int)p[(size_t)E + i];
        if (d < lo || d >= hi) return;
        s = (int)p[i];
    } else {
        const int* p = (const int*)ep;
        d = p[(size_t)E + i];
        if (d < lo || d >= hi) return;
        s = p[i];
    }
    int pos = atomicAdd(&fill[d], 1);
    col[pos] = s;
}

// out[i][:] = bias + dinv[i]*( dinv[i]*t[i][:] + sum_j dinv[col[j]]*t[col[j]][:] )
// t is fp16 (N x 128). 32 lanes per node, 4 halves (8B) per lane; fp32 accum.
__global__ __launch_bounds__(256) void agg_pull_kernel(
    const int* __restrict__ rowp, const int* __restrict__ col,
    const float* __restrict__ dinv, const __half* __restrict__ t,
    const float* __restrict__ bias, float* __restrict__ out, int n) {
    int node = blockIdx.x * 8 + (threadIdx.x >> 5);
    int lane = threadIdx.x & 31;
    if (node >= n) return;
    const uint2* T = (const uint2*)t;  // 4 halves per uint2; 32 per row
    int j0 = rowp[node], j1 = rowp[node + 1];
    float dn = dinv[node];

#define H4_TO_F(raw, fa, fb)                                   \
    float2 fa = __half22float2(*(const __half2*)&raw.x);       \
    float2 fb = __half22float2(*(const __half2*)&raw.y);

    // self-loop: dn * t[node]
    uint2 sraw = T[(size_t)node * 32 + lane];
    H4_TO_F(sraw, s01, s23)
    float4 acc;
    acc.x = s01.x * dn; acc.y = s01.y * dn; acc.z = s23.x * dn; acc.w = s23.y * dn;

    int j = j0;
    for (; j + 3 < j1; j += 4) {
        int c0 = col[j], c1 = col[j + 1], c2 = col[j + 2], c3 = col[j + 3];
        float w0 = dinv[c0], w1 = dinv[c1], w2 = dinv[c2], w3 = dinv[c3];
        uint2 r0 = T[(size_t)c0 * 32 + lane];
        uint2 r1 = T[(size_t)c1 * 32 + lane];
        uint2 r2 = T[(size_t)c2 * 32 + lane];
        uint2 r3 = T[(size_t)c3 * 32 + lane];
        H4_TO_F(r0, a01, a23)
        H4_TO_F(r1, b01, b23)
        H4_TO_F(r2, c01, c23)
        H4_TO_F(r3, d01, d23)
        acc.x = fmaf(a01.x, w0, acc.x); acc.y = fmaf(a01.y, w0, acc.y);
        acc.z = fmaf(a23.x, w0, acc.z); acc.w = fmaf(a23.y, w0, acc.w);
        acc.x = fmaf(b01.x, w1, acc.x); acc.y = fmaf(b01.y, w1, acc.y);
        acc.z = fmaf(b23.x, w1, acc.z); acc.w = fmaf(b23.y, w1, acc.w);
        acc.x = fmaf(c01.x, w2, acc.x); acc.y = fmaf(c01.y, w2, acc.y);
        acc.z = fmaf(c23.x, w2, acc.z); acc.w = fmaf(c23.y, w2, acc.w);
        acc.x = fmaf(d01.x, w3, acc.x); acc.y = fmaf(d01.y, w3, acc.y);
        acc.z = fmaf(d23.x, w3, acc.z); acc.w = fmaf(d23.y, w3, acc.w);
    }
    for (; j < j1; ++j) {
        int c = col[j];
        float w = dinv[c];
        uint2 raw = T[(size_t)c * 32 + lane];
        H4_TO_F(raw, f01, f23)
        acc.x = fmaf(f01.x, w, acc.x); acc.y = fmaf(f01.y, w, acc.y);
        acc.z = fmaf(f23.x, w, acc.z); acc.w = fmaf(f23.y, w, acc.w);
    }
#undef H4_TO_F
    float4 b = ((const float4*)bias)[lane];
    float4 o;
    o.x = fmaf(acc.x, dn, b.x);
    o.y = fmaf(acc.y, dn, b.y);
    o.z = fmaf(acc.z, dn, b.z);
    o.w = fmaf(acc.w, dn, b.w);
    ((float4*)(out + (size_t)node * 128))[lane] = o;
}

// C[n,ncol] = (relu_in? relu(A) : A)[n,128] @ W[128,ncol] (+ bias)
// out_half=1 writes __half C (no bias), else fp32. 64x64 tile, 4x4 micro-tile.
__global__ __launch_bounds__(256) void gemm_k128_kernel(
    const float* __restrict__ A, const float* __restrict__ W,
    const float* __restrict__ bias, void* __restrict__ C,
    int n, int ncol, int relu_in, int out_half) {
    __shared__ float Alds[64 * 128];
    __shared__ float Wlds[128 * 64];
    const int row0 = blockIdx.x * 64;
    const int col0 = blockIdx.y * 64;

    for (int i = threadIdx.x; i < 128 * 64; i += 256) {
        int k = i >> 6, c = i & 63;
        Wlds[i] = W[k * ncol + col0 + c];
    }
    {
        const float4* A4 = (const float4*)A;
        float4* L4 = (float4*)Alds;
        for (int i = threadIdx.x; i < 64 * 32; i += 256) {
            int r = row0 + (i >> 5);
            float4 v = make_float4(0.f, 0.f, 0.f, 0.f);
            if (r < n) v = A4[(size_t)r * 32 + (i & 31)];
            if (relu_in) {
                v.x = fmaxf(v.x, 0.f); v.y = fmaxf(v.y, 0.f);
                v.z = fmaxf(v.z, 0.f); v.w = fmaxf(v.w, 0.f);
            }
            L4[i] = v;
        }
    }
    __syncthreads();

    const int cg = threadIdx.x & 15;
    const int rg = threadIdx.x >> 4;
    float acc[4][4] = {};

#define ACC_ROW(I, AV)                                  \
    acc[I][0] = fmaf(AV.x, w0.x, acc[I][0]);            \
    acc[I][1] = fmaf(AV.x, w0.y, acc[I][1]);            \
    acc[I][2] = fmaf(AV.x, w0.z, acc[I][2]);            \
    acc[I][3] = fmaf(AV.x, w0.w, acc[I][3]);            \
    acc[I][0] = fmaf(AV.y, w1.x, acc[I][0]);            \
    acc[I][1] = fmaf(AV.y, w1.y, acc[I][1]);            \
    acc[I][2] = fmaf(AV.y, w1.z, acc[I][2]);            \
    acc[I][3] = fmaf(AV.y, w1.w, acc[I][3]);            \
    acc[I][0] = fmaf(AV.z, w2.x, acc[I][0]);            \
    acc[I][1] = fmaf(AV.z, w2.y, acc[I][1]);            \
    acc[I][2] = fmaf(AV.z, w2.z, acc[I][2]);            \
    acc[I][3] = fmaf(AV.z, w2.w, acc[I][3]);            \
    acc[I][0] = fmaf(AV.w, w3.x, acc[I][0]);            \
    acc[I][1] = fmaf(AV.w, w3.y, acc[I][1]);            \
    acc[I][2] = fmaf(AV.w, w3.z, acc[I][2]);            \
    acc[I][3] = fmaf(AV.w, w3.w, acc[I][3]);

#pragma unroll 4
    for (int k4 = 0; k4 < 32; ++k4) {
        int k = k4 * 4;
        float4 a0 = *(const float4*)&Alds[(rg * 4 + 0) * 128 + k];
        float4 a1 = *(const float4*)&Alds[(rg * 4 + 1) * 128 + k];
        float4 a2 = *(const float4*)&Alds[(rg * 4 + 2) * 128 + k];
        float4 a3 = *(const float4*)&Alds[(rg * 4 + 3) * 128 + k];
        float4 w0 = *(const float4*)&Wlds[(k + 0) * 64 + cg * 4];
        float4 w1 = *(const float4*)&Wlds[(k + 1) * 64 + cg * 4];
        float4 w2 = *(const float4*)&Wlds[(k + 2) * 64 + cg * 4];
        float4 w3 = *(const float4*)&Wlds[(k + 3) * 64 + cg * 4];
        ACC_ROW(0, a0)
        ACC_ROW(1, a1)
        ACC_ROW(2, a2)
        ACC_ROW(3, a3)
    }
#undef ACC_ROW

    float4 b4 = make_float4(0.f, 0.f, 0.f, 0.f);
    if (bias) b4 = *(const float4*)&bias[col0 + cg * 4];
#pragma unroll
    for (int i = 0; i < 4; ++i) {
        int r = row0 + rg * 4 + i;
        if (r >= n) continue;
        float4 o;
        o.x = acc[i][0] + b4.x;
        o.y = acc[i][1] + b4.y;
        o.z = acc[i][2] + b4.z;
        o.w = acc[i][3] + b4.w;
        if (out_half) {
            __half2 h01 = __floats2half2_rn(o.x, o.y);
            __half2 h23 = __floats2half2_rn(o.z, o.w);
            uint2 packed;
            packed.x = *(unsigned*)&h01;
            packed.y = *(unsigned*)&h23;
            *(uint2*)&((__half*)C)[(size_t)r * ncol + col0 + cg * 4] = packed;
        } else {
            *(float4*)&((float*)C)[(size_t)r * ncol + col0 + cg * 4] = o;
        }
    }
}

extern "C" void kernel_launch(void* const* d_in, const int* in_sizes, int n_in,
                              void* d_out, int out_size, void* d_ws, size_t ws_size,
                              hipStream_t stream) {
    const float* x  = (const float*)d_in[0];
    const void*  ei = d_in[1];
    const float* We = (const float*)d_in[2];
    const float* be = (const float*)d_in[3];
    const float* W1 = (const float*)d_in[4];
    const float* b1 = (const float*)d_in[5];
    const float* W2 = (const float*)d_in[6];
    const float* b2 = (const float*)d_in[7];
    const float* Wo = (const float*)d_in[8];
    const float* bo = (const float*)d_in[9];
    const int N = in_sizes[0] / 128;
    const int E = in_sizes[1] / 2;

    char* ws = (char*)d_ws;
    size_t off = 0;
    int*      flag = (int*)(ws + off);      off += 256;
    unsigned* ecnt = (unsigned*)(ws + off); off += WS_ALIGN((size_t)N * 4);
    float*    dinv = (float*)(ws + off);    off += WS_ALIGN((size_t)N * 4);
    int*      rowp = (int*)(ws + off);      off += WS_ALIGN((size_t)(N + 1) * 4);
    int*      fill = (int*)(ws + off);      off += WS_ALIGN((size_t)N * 4);
    int*      colw = (int*)(ws + off);      off += WS_ALIGN((size_t)E * 4);
    __half*   tH   = (__half*)(ws + off);   off += WS_ALIGN((size_t)N * 128 * 2);
    float*    bufA = (float*)(ws + off);    off += WS_ALIGN((size_t)N * 128 * 4);
    float*    bufB = (float*)(ws + off);    off += WS_ALIGN((size_t)N * 128 * 4);

    const int nb_n = (N + 255) / 256;
    const int nb_e = (E + 255) / 256;

    // CSR build (edges only) + normalization
    detect_i64_kernel<<<1, 256, 0, stream>>>((const unsigned*)ei, flag);
    zero_u32_kernel<<<nb_n, 256, 0, stream>>>(ecnt, N);
    count_deg_kernel<<<nb_e, 256, 0, stream>>>(ei, flag, ecnt, E);
    scan_kernel<<<1, 1024, 0, stream>>>(ecnt, rowp, N);
    finalize_kernel<<<nb_n, 256, 0, stream>>>(ecnt, rowp, dinv, fill, N);
    edge_fill_part_kernel<<<nb_e * 8, 256, 0, stream>>>(ei, flag, fill, colw, E, N);

    dim3 blk(256);
    dim3 g128((N + 63) / 64, 2);
    dim3 g64((N + 63) / 64, 1);
    const int agg_blocks = (N + 7) / 8;

    // encoder: h0 = x@We + be -> bufA (fp32)
    gemm_k128_kernel<<<g128, blk, 0, stream>>>(x, We, be, bufA, N, 128, 0, 0);
    // conv1: t1 = h0@W1 -> tH (fp16) ; out1 = Agg(t1)+b1 -> bufB
    gemm_k128_kernel<<<g128, blk, 0, stream>>>(bufA, W1, nullptr, tH, N, 128, 0, 1);
    agg_pull_kernel<<<agg_blocks, blk, 0, stream>>>(rowp, colw, dinv, tH, b1, bufB, N);
    // conv2: t2 = relu(out1)@W2 -> tH ; out2 = Agg(t2)+b2 -> bufA
    gemm_k128_kernel<<<g128, blk, 0, stream>>>(bufB, W2, nullptr, tH, N, 128, 1, 1);
    agg_pull_kernel<<<agg_blocks, blk, 0, stream>>>(rowp, colw, dinv, tH, b2, bufA, N);
    // decoder: out = relu(out2)@Wo + bo -> d_out (fp32)
    gemm_k128_kernel<<<g64, blk, 0, stream>>>(bufA, Wo, bo, d_out, N, 64, 1, 0);
}

// Round 7
// 416.746 us; speedup vs baseline: 1.6478x; 1.1707x over previous
//
#include <hip/hip_runtime.h>
#include <hip/hip_fp16.h>

// ---------------------------------------------------------------------------
// GCN: out = (relu(conv2(relu(conv1(x@We+be)))))@Wo + bo
// conv(h): t = h@W (fp16);  out[i] = b + dinv[i]*( dinv[i]*t[i] + sum dinv[s]*t[s] )
// CSR (edges only, by dst): count -> 3-phase scan -> XCD-partitioned atomic fill.
// ---------------------------------------------------------------------------

#define WS_ALIGN(x) (((x) + 255) & ~(size_t)255)
#define SCAN_BLOCKS 256
#define SCAN_TPB 256

// flag=1 => edge_index is int64, flag=0 => int32
__global__ void detect_i64_kernel(const unsigned* __restrict__ p, int* __restrict__ flag) {
    __shared__ int any;
    if (threadIdx.x == 0) any = 0;
    __syncthreads();
    int nz = 0;
    for (int i = threadIdx.x; i < 2048; i += blockDim.x)
        nz |= (p[2 * i + 1] != 0u) ? 1 : 0;
    if (nz) atomicOr(&any, 1);
    __syncthreads();
    if (threadIdx.x == 0) *flag = (any == 0) ? 1 : 0;
}

__global__ void zero_u32_kernel(unsigned* __restrict__ a, int n) {
    int i = blockIdx.x * blockDim.x + threadIdx.x;
    if (i < n) a[i] = 0u;
}

__global__ void count_deg_kernel(const void* __restrict__ ep, const int* __restrict__ flag,
                                 unsigned* __restrict__ ecnt, int E) {
    int i = blockIdx.x * blockDim.x + threadIdx.x;
    if (i >= E) return;
    int d = (*flag) ? (int)((const long long*)ep)[(size_t)E + i]
                    : ((const int*)ep)[(size_t)E + i];
    atomicAdd(&ecnt[d], 1u);
}

// -------- 3-phase device-wide exclusive scan of ecnt -> row_ptr ------------
// Phase A: blocksum[b] = sum of ecnt over block b's chunk (coalesced).
__global__ __launch_bounds__(SCAN_TPB) void scan_phaseA_kernel(
    const unsigned* __restrict__ ecnt, unsigned* __restrict__ blocksum, int n) {
    const int b = blockIdx.x;
    const int chunk = (n + SCAN_BLOCKS - 1) / SCAN_BLOCKS;
    const int i0 = b * chunk;
    const int i1 = min(i0 + chunk, n);
    unsigned s = 0;
    for (int i = i0 + threadIdx.x; i < i1; i += SCAN_TPB) s += ecnt[i];
    __shared__ unsigned red[SCAN_TPB / 64];
    for (int off = 32; off; off >>= 1) s += __shfl_down(s, off, 64);
    const int wid = threadIdx.x >> 6;
    if ((threadIdx.x & 63) == 0) red[wid] = s;
    __syncthreads();
    if (threadIdx.x == 0) {
        unsigned t = 0;
        for (int w = 0; w < SCAN_TPB / 64; ++w) t += red[w];
        blocksum[b] = t;
    }
}

// Phase B: in-place exclusive scan of the SCAN_BLOCKS block sums.
__global__ __launch_bounds__(SCAN_BLOCKS) void scan_phaseB_kernel(unsigned* __restrict__ blocksum) {
    __shared__ unsigned lds[SCAN_BLOCKS];
    const int tid = threadIdx.x;
    lds[tid] = blocksum[tid];
    __syncthreads();
    for (int off = 1; off < SCAN_BLOCKS; off <<= 1) {
        unsigned add = (tid >= off) ? lds[tid - off] : 0;
        __syncthreads();
        lds[tid] += add;
        __syncthreads();
    }
    blocksum[tid] = (tid > 0) ? lds[tid - 1] : 0;
}

// Phase C: local scan + block offset -> row_ptr[i] (row start), fill[i], dinv[i].
// Also row_ptr[n] = E.
__global__ __launch_bounds__(SCAN_TPB) void scan_phaseC_kernel(
    const unsigned* __restrict__ ecnt, const unsigned* __restrict__ blocksum,
    int* __restrict__ row_ptr, int* __restrict__ fill, float* __restrict__ dinv,
    int n, int E) {
    const int b = blockIdx.x;
    const int chunk = (n + SCAN_BLOCKS - 1) / SCAN_BLOCKS;
    const int i0 = b * chunk;
    const int i1 = min(i0 + chunk, n);
    const int sub = (chunk + SCAN_TPB - 1) / SCAN_TPB;
    const int t0 = i0 + threadIdx.x * sub;
    const int t1 = min(t0 + sub, i1);
    __shared__ unsigned part[SCAN_TPB];
    unsigned s = 0;
    for (int i = t0; i < t1; ++i) s += ecnt[i];
    part[threadIdx.x] = s;
    __syncthreads();
    for (int off = 1; off < SCAN_TPB; off <<= 1) {
        unsigned add = (threadIdx.x >= off) ? part[threadIdx.x - off] : 0;
        __syncthreads();
        part[threadIdx.x] += add;
        __syncthreads();
    }
    unsigned run = blocksum[b] + ((threadIdx.x > 0) ? part[threadIdx.x - 1] : 0);
    for (int i = t0; i < t1; ++i) {
        unsigned e = ecnt[i];
        row_ptr[i] = (int)run;
        fill[i] = (int)run;
        dinv[i] = rsqrtf((float)(e + 1u));
        run += e;
    }
    if (b == 0 && threadIdx.x == 0) row_ptr[n] = E;
}

// XCD-partitioned fill: part = bid&7 owns dst range [part*rs, part*rs+rs).
__global__ __launch_bounds__(256) void edge_fill_part_kernel(
    const void* __restrict__ ep, const int* __restrict__ flag,
    int* __restrict__ fill, int* __restrict__ col, int E, int n) {
    int part = blockIdx.x & 7;
    int i = (blockIdx.x >> 3) * 256 + threadIdx.x;
    if (i >= E) return;
    const int rs = (n + 7) >> 3;
    const int lo = part * rs;
    const int hi = min(lo + rs, n);
    int s, d;
    if (*flag) {
        const long long* p = (const long long*)ep;
        d = (int)p[(size_t)E + i];
        if (d < lo || d >= hi) return;
        s = (int)p[i];
    } else {
        const int* p = (const int*)ep;
        d = p[(size_t)E + i];
        if (d < lo || d >= hi) return;
        s = p[i];
    }
    int pos = atomicAdd(&fill[d], 1);
    col[pos] = s;
}

// out[i][:] = bias + dinv[i]*( dinv[i]*t[i][:] + sum_j dinv[col[j]]*t[col[j]][:] )
// t is fp16 (N x 128). 32 lanes per node, 4 halves (8B) per lane; fp32 accum.
__global__ __launch_bounds__(256) void agg_pull_kernel(
    const int* __restrict__ rowp, const int* __restrict__ col,
    const float* __restrict__ dinv, const __half* __restrict__ t,
    const float* __restrict__ bias, float* __restrict__ out, int n) {
    int node = blockIdx.x * 8 + (threadIdx.x >> 5);
    int lane = threadIdx.x & 31;
    if (node >= n) return;
    const uint2* T = (const uint2*)t;
    int j0 = rowp[node], j1 = rowp[node + 1];
    float dn = dinv[node];

#define H4_TO_F(raw, fa, fb)                                   \
    float2 fa = __half22float2(*(const __half2*)&raw.x);       \
    float2 fb = __half22float2(*(const __half2*)&raw.y);

    uint2 sraw = T[(size_t)node * 32 + lane];
    H4_TO_F(sraw, s01, s23)
    float4 acc;
    acc.x = s01.x * dn; acc.y = s01.y * dn; acc.z = s23.x * dn; acc.w = s23.y * dn;

    int j = j0;
    for (; j + 3 < j1; j += 4) {
        int c0 = col[j], c1 = col[j + 1], c2 = col[j + 2], c3 = col[j + 3];
        float w0 = dinv[c0], w1 = dinv[c1], w2 = dinv[c2], w3 = dinv[c3];
        uint2 r0 = T[(size_t)c0 * 32 + lane];
        uint2 r1 = T[(size_t)c1 * 32 + lane];
        uint2 r2 = T[(size_t)c2 * 32 + lane];
        uint2 r3 = T[(size_t)c3 * 32 + lane];
        H4_TO_F(r0, a01, a23)
        H4_TO_F(r1, b01, b23)
        H4_TO_F(r2, c01, c23)
        H4_TO_F(r3, d01, d23)
        acc.x = fmaf(a01.x, w0, acc.x); acc.y = fmaf(a01.y, w0, acc.y);
        acc.z = fmaf(a23.x, w0, acc.z); acc.w = fmaf(a23.y, w0, acc.w);
        acc.x = fmaf(b01.x, w1, acc.x); acc.y = fmaf(b01.y, w1, acc.y);
        acc.z = fmaf(b23.x, w1, acc.z); acc.w = fmaf(b23.y, w1, acc.w);
        acc.x = fmaf(c01.x, w2, acc.x); acc.y = fmaf(c01.y, w2, acc.y);
        acc.z = fmaf(c23.x, w2, acc.z); acc.w = fmaf(c23.y, w2, acc.w);
        acc.x = fmaf(d01.x, w3, acc.x); acc.y = fmaf(d01.y, w3, acc.y);
        acc.z = fmaf(d23.x, w3, acc.z); acc.w = fmaf(d23.y, w3, acc.w);
    }
    for (; j < j1; ++j) {
        int c = col[j];
        float w = dinv[c];
        uint2 raw = T[(size_t)c * 32 + lane];
        H4_TO_F(raw, f01, f23)
        acc.x = fmaf(f01.x, w, acc.x); acc.y = fmaf(f01.y, w, acc.y);
        acc.z = fmaf(f23.x, w, acc.z); acc.w = fmaf(f23.y, w, acc.w);
    }
#undef H4_TO_F
    float4 b = ((const float4*)bias)[lane];
    float4 o;
    o.x = fmaf(acc.x, dn, b.x);
    o.y = fmaf(acc.y, dn, b.y);
    o.z = fmaf(acc.z, dn, b.z);
    o.w = fmaf(acc.w, dn, b.w);
    ((float4*)(out + (size_t)node * 128))[lane] = o;
}

// C[n,ncol] = (relu_in? relu(A) : A)[n,128] @ W[128,ncol] (+ bias)
// out_half=1 writes __half C (no bias), else fp32. 64x64 tile, 4x4 micro-tile.
__global__ __launch_bounds__(256) void gemm_k128_kernel(
    const float* __restrict__ A, const float* __restrict__ W,
    const float* __restrict__ bias, void* __restrict__ C,
    int n, int ncol, int relu_in, int out_half) {
    __shared__ float Alds[64 * 128];
    __shared__ float Wlds[128 * 64];
    const int row0 = blockIdx.x * 64;
    const int col0 = blockIdx.y * 64;

    for (int i = threadIdx.x; i < 128 * 64; i += 256) {
        int k = i >> 6, c = i & 63;
        Wlds[i] = W[k * ncol + col0 + c];
    }
    {
        const float4* A4 = (const float4*)A;
        float4* L4 = (float4*)Alds;
        for (int i = threadIdx.x; i < 64 * 32; i += 256) {
            int r = row0 + (i >> 5);
            float4 v = make_float4(0.f, 0.f, 0.f, 0.f);
            if (r < n) v = A4[(size_t)r * 32 + (i & 31)];
            if (relu_in) {
                v.x = fmaxf(v.x, 0.f); v.y = fmaxf(v.y, 0.f);
                v.z = fmaxf(v.z, 0.f); v.w = fmaxf(v.w, 0.f);
            }
            L4[i] = v;
        }
    }
    __syncthreads();

    const int cg = threadIdx.x & 15;
    const int rg = threadIdx.x >> 4;
    float acc[4][4] = {};

#define ACC_ROW(I, AV)                                  \
    acc[I][0] = fmaf(AV.x, w0.x, acc[I][0]);            \
    acc[I][1] = fmaf(AV.x, w0.y, acc[I][1]);            \
    acc[I][2] = fmaf(AV.x, w0.z, acc[I][2]);            \
    acc[I][3] = fmaf(AV.x, w0.w, acc[I][3]);            \
    acc[I][0] = fmaf(AV.y, w1.x, acc[I][0]);            \
    acc[I][1] = fmaf(AV.y, w1.y, acc[I][1]);            \
    acc[I][2] = fmaf(AV.y, w1.z, acc[I][2]);            \
    acc[I][3] = fmaf(AV.y, w1.w, acc[I][3]);            \
    acc[I][0] = fmaf(AV.z, w2.x, acc[I][0]);            \
    acc[I][1] = fmaf(AV.z, w2.y, acc[I][1]);            \
    acc[I][2] = fmaf(AV.z, w2.z, acc[I][2]);            \
    acc[I][3] = fmaf(AV.z, w2.w, acc[I][3]);            \
    acc[I][0] = fmaf(AV.w, w3.x, acc[I][0]);            \
    acc[I][1] = fmaf(AV.w, w3.y, acc[I][1]);            \
    acc[I][2] = fmaf(AV.w, w3.z, acc[I][2]);            \
    acc[I][3] = fmaf(AV.w, w3.w, acc[I][3]);

#pragma unroll 4
    for (int k4 = 0; k4 < 32; ++k4) {
        int k = k4 * 4;
        float4 a0 = *(const float4*)&Alds[(rg * 4 + 0) * 128 + k];
        float4 a1 = *(const float4*)&Alds[(rg * 4 + 1) * 128 + k];
        float4 a2 = *(const float4*)&Alds[(rg * 4 + 2) * 128 + k];
        float4 a3 = *(const float4*)&Alds[(rg * 4 + 3) * 128 + k];
        float4 w0 = *(const float4*)&Wlds[(k + 0) * 64 + cg * 4];
        float4 w1 = *(const float4*)&Wlds[(k + 1) * 64 + cg * 4];
        float4 w2 = *(const float4*)&Wlds[(k + 2) * 64 + cg * 4];
        float4 w3 = *(const float4*)&Wlds[(k + 3) * 64 + cg * 4];
        ACC_ROW(0, a0)
        ACC_ROW(1, a1)
        ACC_ROW(2, a2)
        ACC_ROW(3, a3)
    }
#undef ACC_ROW

    float4 b4 = make_float4(0.f, 0.f, 0.f, 0.f);
    if (bias) b4 = *(const float4*)&bias[col0 + cg * 4];
#pragma unroll
    for (int i = 0; i < 4; ++i) {
        int r = row0 + rg * 4 + i;
        if (r >= n) continue;
        float4 o;
        o.x = acc[i][0] + b4.x;
        o.y = acc[i][1] + b4.y;
        o.z = acc[i][2] + b4.z;
        o.w = acc[i][3] + b4.w;
        if (out_half) {
            __half2 h01 = __floats2half2_rn(o.x, o.y);
            __half2 h23 = __floats2half2_rn(o.z, o.w);
            uint2 packed;
            packed.x = *(unsigned*)&h01;
            packed.y = *(unsigned*)&h23;
            *(uint2*)&((__half*)C)[(size_t)r * ncol + col0 + cg * 4] = packed;
        } else {
            *(float4*)&((float*)C)[(size_t)r * ncol + col0 + cg * 4] = o;
        }
    }
}

extern "C" void kernel_launch(void* const* d_in, const int* in_sizes, int n_in,
                              void* d_out, int out_size, void* d_ws, size_t ws_size,
                              hipStream_t stream) {
    const float* x  = (const float*)d_in[0];
    const void*  ei = d_in[1];
    const float* We = (const float*)d_in[2];
    const float* be = (const float*)d_in[3];
    const float* W1 = (const float*)d_in[4];
    const float* b1 = (const float*)d_in[5];
    const float* W2 = (const float*)d_in[6];
    const float* b2 = (const float*)d_in[7];
    const float* Wo = (const float*)d_in[8];
    const float* bo = (const float*)d_in[9];
    const int N = in_sizes[0] / 128;
    const int E = in_sizes[1] / 2;

    char* ws = (char*)d_ws;
    size_t off = 0;
    int*      flag = (int*)(ws + off);      off += 256;
    unsigned* bsum = (unsigned*)(ws + off); off += WS_ALIGN((size_t)SCAN_BLOCKS * 4);
    unsigned* ecnt = (unsigned*)(ws + off); off += WS_ALIGN((size_t)N * 4);
    float*    dinv = (float*)(ws + off);    off += WS_ALIGN((size_t)N * 4);
    int*      rowp = (int*)(ws + off);      off += WS_ALIGN((size_t)(N + 1) * 4);
    int*      fill = (int*)(ws + off);      off += WS_ALIGN((size_t)N * 4);
    int*      colw = (int*)(ws + off);      off += WS_ALIGN((size_t)E * 4);
    __half*   tH   = (__half*)(ws + off);   off += WS_ALIGN((size_t)N * 128 * 2);
    float*    bufA = (float*)(ws + off);    off += WS_ALIGN((size_t)N * 128 * 4);
    float*    bufB = (float*)(ws + off);    off += WS_ALIGN((size_t)N * 128 * 4);

    const int nb_n = (N + 255) / 256;
    const int nb_e = (E + 255) / 256;

    // CSR build (edges only) + normalization
    detect_i64_kernel<<<1, 256, 0, stream>>>((const unsigned*)ei, flag);
    zero_u32_kernel<<<nb_n, 256, 0, stream>>>(ecnt, N);
    count_deg_kernel<<<nb_e, 256, 0, stream>>>(ei, flag, ecnt, E);
    scan_phaseA_kernel<<<SCAN_BLOCKS, SCAN_TPB, 0, stream>>>(ecnt, bsum, N);
    scan_phaseB_kernel<<<1, SCAN_BLOCKS, 0, stream>>>(bsum);
    scan_phaseC_kernel<<<SCAN_BLOCKS, SCAN_TPB, 0, stream>>>(ecnt, bsum, rowp, fill, dinv, N, E);
    edge_fill_part_kernel<<<nb_e * 8, 256, 0, stream>>>(ei, flag, fill, colw, E, N);

    dim3 blk(256);
    dim3 g128((N + 63) / 64, 2);
    dim3 g64((N + 63) / 64, 1);
    const int agg_blocks = (N + 7) / 8;

    // encoder: h0 = x@We + be -> bufA (fp32)
    gemm_k128_kernel<<<g128, blk, 0, stream>>>(x, We, be, bufA, N, 128, 0, 0);
    // conv1: t1 = h0@W1 -> tH (fp16) ; out1 = Agg(t1)+b1 -> bufB
    gemm_k128_kernel<<<g128, blk, 0, stream>>>(bufA, W1, nullptr, tH, N, 128, 0, 1);
    agg_pull_kernel<<<agg_blocks, blk, 0, stream>>>(rowp, colw, dinv, tH, b1, bufB, N);
    // conv2: t2 = relu(out1)@W2 -> tH ; out2 = Agg(t2)+b2 -> bufA
    gemm_k128_kernel<<<g128, blk, 0, stream>>>(bufB, W2, nullptr, tH, N, 128, 1, 1);
    agg_pull_kernel<<<agg_blocks, blk, 0, stream>>>(rowp, colw, dinv, tH, b2, bufA, N);
    // decoder: out = relu(out2)@Wo + bo -> d_out (fp32)
    gemm_k128_kernel<<<g64, blk, 0, stream>>>(bufA, Wo, bo, d_out, N, 64, 1, 0);
}

// Round 8
// 340.487 us; speedup vs baseline: 2.0169x; 1.2240x over previous
//
#include <hip/hip_runtime.h>
#include <hip/hip_fp16.h>

// ---------------------------------------------------------------------------
// GCN: out = (relu(conv2(relu(conv1(x@We+be)))))@Wo + bo
// All GEMMs: fp16 inputs via MFMA 16x16x32_f16, fp32 accum.
// conv(h): t = h@W (fp16); out[i] = relu(b + dinv[i]*(dinv[i]*t[i] + sum dinv[s]*t[s]))
// CSR (edges only, by dst): int32 convert -> count -> 3-phase scan -> XCD-part fill.
// ---------------------------------------------------------------------------

#define WS_ALIGN(x) (((x) + 255) & ~(size_t)255)
#define SCAN_BLOCKS 256
#define SCAN_TPB 256

typedef _Float16 f16x8 __attribute__((ext_vector_type(8)));
typedef float f32x4 __attribute__((ext_vector_type(4)));

// flag=1 => edge_index is int64, flag=0 => int32
__global__ void detect_i64_kernel(const unsigned* __restrict__ p, int* __restrict__ flag) {
    __shared__ int any;
    if (threadIdx.x == 0) any = 0;
    __syncthreads();
    int nz = 0;
    for (int i = threadIdx.x; i < 2048; i += blockDim.x)
        nz |= (p[2 * i + 1] != 0u) ? 1 : 0;
    if (nz) atomicOr(&any, 1);
    __syncthreads();
    if (threadIdx.x == 0) *flag = (any == 0) ? 1 : 0;
}

__global__ void convert_edges_kernel(const void* __restrict__ ep, const int* __restrict__ flag,
                                     int* __restrict__ src, int* __restrict__ dst, int E) {
    int i = blockIdx.x * blockDim.x + threadIdx.x;
    if (i >= E) return;
    if (*flag) {
        const long long* p = (const long long*)ep;
        src[i] = (int)p[i];
        dst[i] = (int)p[(size_t)E + i];
    } else {
        const int* p = (const int*)ep;
        src[i] = p[i];
        dst[i] = p[(size_t)E + i];
    }
}

__global__ void zero_u32_kernel(unsigned* __restrict__ a, int n) {
    int i = blockIdx.x * blockDim.x + threadIdx.x;
    if (i < n) a[i] = 0u;
}

__global__ void count_deg_kernel(const int* __restrict__ dst, unsigned* __restrict__ ecnt, int E) {
    int i = blockIdx.x * blockDim.x + threadIdx.x;
    if (i < E) atomicAdd(&ecnt[dst[i]], 1u);
}

// -------- 3-phase device-wide exclusive scan of ecnt -> row_ptr ------------
__global__ __launch_bounds__(SCAN_TPB) void scan_phaseA_kernel(
    const unsigned* __restrict__ ecnt, unsigned* __restrict__ blocksum, int n) {
    const int b = blockIdx.x;
    const int chunk = (n + SCAN_BLOCKS - 1) / SCAN_BLOCKS;
    const int i0 = b * chunk;
    const int i1 = min(i0 + chunk, n);
    unsigned s = 0;
    for (int i = i0 + threadIdx.x; i < i1; i += SCAN_TPB) s += ecnt[i];
    __shared__ unsigned red[SCAN_TPB / 64];
    for (int off = 32; off; off >>= 1) s += __shfl_down(s, off, 64);
    const int wid = threadIdx.x >> 6;
    if ((threadIdx.x & 63) == 0) red[wid] = s;
    __syncthreads();
    if (threadIdx.x == 0) {
        unsigned t = 0;
        for (int w = 0; w < SCAN_TPB / 64; ++w) t += red[w];
        blocksum[b] = t;
    }
}

__global__ __launch_bounds__(SCAN_BLOCKS) void scan_phaseB_kernel(unsigned* __restrict__ blocksum) {
    __shared__ unsigned lds[SCAN_BLOCKS];
    const int tid = threadIdx.x;
    lds[tid] = blocksum[tid];
    __syncthreads();
    for (int off = 1; off < SCAN_BLOCKS; off <<= 1) {
        unsigned add = (tid >= off) ? lds[tid - off] : 0;
        __syncthreads();
        lds[tid] += add;
        __syncthreads();
    }
    blocksum[tid] = (tid > 0) ? lds[tid - 1] : 0;
}

__global__ __launch_bounds__(SCAN_TPB) void scan_phaseC_kernel(
    const unsigned* __restrict__ ecnt, const unsigned* __restrict__ blocksum,
    int* __restrict__ row_ptr, int* __restrict__ fill, float* __restrict__ dinv,
    int n, int E) {
    const int b = blockIdx.x;
    const int chunk = (n + SCAN_BLOCKS - 1) / SCAN_BLOCKS;
    const int i0 = b * chunk;
    const int i1 = min(i0 + chunk, n);
    const int sub = (chunk + SCAN_TPB - 1) / SCAN_TPB;
    const int t0 = i0 + threadIdx.x * sub;
    const int t1 = min(t0 + sub, i1);
    __shared__ unsigned part[SCAN_TPB];
    unsigned s = 0;
    for (int i = t0; i < t1; ++i) s += ecnt[i];
    part[threadIdx.x] = s;
    __syncthreads();
    for (int off = 1; off < SCAN_TPB; off <<= 1) {
        unsigned add = (threadIdx.x >= off) ? part[threadIdx.x - off] : 0;
        __syncthreads();
        part[threadIdx.x] += add;
        __syncthreads();
    }
    unsigned run = blocksum[b] + ((threadIdx.x > 0) ? part[threadIdx.x - 1] : 0);
    for (int i = t0; i < t1; ++i) {
        unsigned e = ecnt[i];
        row_ptr[i] = (int)run;
        fill[i] = (int)run;
        dinv[i] = rsqrtf((float)(e + 1u));
        run += e;
    }
    if (b == 0 && threadIdx.x == 0) row_ptr[n] = E;
}

// XCD-partitioned fill: part = bid&7 owns dst range. Non-temporal dst reads
// keep the L2 free for the partition's col lines (write-combining in cache).
__global__ __launch_bounds__(256) void edge_fill_part_kernel(
    const int* __restrict__ src, const int* __restrict__ dst,
    int* __restrict__ fill, int* __restrict__ col, int E, int n) {
    int part = blockIdx.x & 7;
    int i = (blockIdx.x >> 3) * 256 + threadIdx.x;
    if (i >= E) return;
    const int rs = (n + 7) >> 3;
    const int lo = part * rs;
    const int hi = min(lo + rs, n);
    int d = __builtin_nontemporal_load(dst + i);
    if (d < lo || d >= hi) return;
    int s = __builtin_nontemporal_load(src + i);
    int pos = atomicAdd(&fill[d], 1);
    col[pos] = s;
}

// out[i][:] = relu( bias + dinv[i]*( dinv[i]*t[i][:] + sum_j dinv[col[j]]*t[col[j]][:] ) )
// t fp16 (N x 128); out fp16. 32 lanes/node, 4 halves per lane; fp32 accum.
__global__ __launch_bounds__(256) void agg_pull_kernel(
    const int* __restrict__ rowp, const int* __restrict__ col,
    const float* __restrict__ dinv, const __half* __restrict__ t,
    const float* __restrict__ bias, __half* __restrict__ out, int n) {
    int node = blockIdx.x * 8 + (threadIdx.x >> 5);
    int lane = threadIdx.x & 31;
    if (node >= n) return;
    const uint2* T = (const uint2*)t;
    int j0 = rowp[node], j1 = rowp[node + 1];
    float dn = dinv[node];

#define H4_TO_F(raw, fa, fb)                                   \
    float2 fa = __half22float2(*(const __half2*)&raw.x);       \
    float2 fb = __half22float2(*(const __half2*)&raw.y);

    uint2 sraw = T[(size_t)node * 32 + lane];
    H4_TO_F(sraw, s01, s23)
    float4 acc;
    acc.x = s01.x * dn; acc.y = s01.y * dn; acc.z = s23.x * dn; acc.w = s23.y * dn;

    int j = j0;
    for (; j + 3 < j1; j += 4) {
        int c0 = col[j], c1 = col[j + 1], c2 = col[j + 2], c3 = col[j + 3];
        float w0 = dinv[c0], w1 = dinv[c1], w2 = dinv[c2], w3 = dinv[c3];
        uint2 r0 = T[(size_t)c0 * 32 + lane];
        uint2 r1 = T[(size_t)c1 * 32 + lane];
        uint2 r2 = T[(size_t)c2 * 32 + lane];
        uint2 r3 = T[(size_t)c3 * 32 + lane];
        H4_TO_F(r0, a01, a23)
        H4_TO_F(r1, b01, b23)
        H4_TO_F(r2, c01, c23)
        H4_TO_F(r3, d01, d23)
        acc.x = fmaf(a01.x, w0, acc.x); acc.y = fmaf(a01.y, w0, acc.y);
        acc.z = fmaf(a23.x, w0, acc.z); acc.w = fmaf(a23.y, w0, acc.w);
        acc.x = fmaf(b01.x, w1, acc.x); acc.y = fmaf(b01.y, w1, acc.y);
        acc.z = fmaf(b23.x, w1, acc.z); acc.w = fmaf(b23.y, w1, acc.w);
        acc.x = fmaf(c01.x, w2, acc.x); acc.y = fmaf(c01.y, w2, acc.y);
        acc.z = fmaf(c23.x, w2, acc.z); acc.w = fmaf(c23.y, w2, acc.w);
        acc.x = fmaf(d01.x, w3, acc.x); acc.y = fmaf(d01.y, w3, acc.y);
        acc.z = fmaf(d23.x, w3, acc.z); acc.w = fmaf(d23.y, w3, acc.w);
    }
    for (; j < j1; ++j) {
        int c = col[j];
        float w = dinv[c];
        uint2 raw = T[(size_t)c * 32 + lane];
        H4_TO_F(raw, f01, f23)
        acc.x = fmaf(f01.x, w, acc.x); acc.y = fmaf(f01.y, w, acc.y);
        acc.z = fmaf(f23.x, w, acc.z); acc.w = fmaf(f23.y, w, acc.w);
    }
#undef H4_TO_F
    float4 b = ((const float4*)bias)[lane];
    float ox = fmaxf(fmaf(acc.x, dn, b.x), 0.f);
    float oy = fmaxf(fmaf(acc.y, dn, b.y), 0.f);
    float oz = fmaxf(fmaf(acc.z, dn, b.z), 0.f);
    float ow = fmaxf(fmaf(acc.w, dn, b.w), 0.f);
    __half2 h01 = __floats2half2_rn(ox, oy);
    __half2 h23 = __floats2half2_rn(oz, ow);
    uint2 packed;
    packed.x = *(unsigned*)&h01;
    packed.y = *(unsigned*)&h23;
    ((uint2*)(out + (size_t)node * 128))[lane] = packed;
}

// fp32 -> fp16, 8 elems/thread
__global__ void f32_to_f16_kernel(const float* __restrict__ in, __half* __restrict__ out, int n8) {
    int i = blockIdx.x * blockDim.x + threadIdx.x;
    if (i >= n8) return;
    const float4* in4 = (const float4*)in;
    float4 v0 = in4[2 * i], v1 = in4[2 * i + 1];
    __half2 h0 = __floats2half2_rn(v0.x, v0.y);
    __half2 h1 = __floats2half2_rn(v0.z, v0.w);
    __half2 h2 = __floats2half2_rn(v1.x, v1.y);
    __half2 h3 = __floats2half2_rn(v1.z, v1.w);
    uint4 p;
    p.x = *(unsigned*)&h0; p.y = *(unsigned*)&h1;
    p.z = *(unsigned*)&h2; p.w = *(unsigned*)&h3;
    *(uint4*)(out + (size_t)i * 8) = p;
}

// Build fragment-ready W: Wf[((c0*4+ks)*64+lane)*8+j] = f16(W[ks*32+(lane>>4)*8+j][c0*16+(lane&15)])
__global__ void wfrag_kernel(const float* __restrict__ W, __half* __restrict__ Wf, int ncol) {
    int t = blockIdx.x * blockDim.x + threadIdx.x;  // (c0*4+ks)*64 + lane
    int total = (ncol >> 4) * 4 * 64;
    if (t >= total) return;
    int lane = t & 63;
    int ks = (t >> 6) & 3;
    int c0 = t >> 8;
    int colw = c0 * 16 + (lane & 15);
    int k0 = ks * 32 + ((lane >> 4) << 3);
    __half vals[8];
#pragma unroll
    for (int j = 0; j < 8; ++j) vals[j] = __float2half(W[(size_t)(k0 + j) * ncol + colw]);
    *(uint4*)(Wf + (size_t)t * 8) = *(uint4*)vals;
}

// C[n,ncol] = A[n,128](f16) @ W[128,ncol] (+bias). MFMA f16, fp32 accum.
// Block = 4 waves x 16 rows = 64 rows. Wave loads 4 A-frags; loops col-chunks.
__global__ __launch_bounds__(256) void gemm_mfma_kernel(
    const __half* __restrict__ A, const __half* __restrict__ Wf,
    const float* __restrict__ bias, void* __restrict__ C,
    int n, int ncol, int c_fp32) {
    const int wave = threadIdx.x >> 6;
    const int lane = threadIdx.x & 63;
    const int row0 = blockIdx.x * 64 + wave * 16;
    int ar = row0 + (lane & 15);
    if (ar >= n) ar = n - 1;
    const __half* abase = A + (size_t)ar * 128 + ((lane >> 4) << 3);
    f16x8 a0 = *(const f16x8*)(abase);
    f16x8 a1 = *(const f16x8*)(abase + 32);
    f16x8 a2 = *(const f16x8*)(abase + 64);
    f16x8 a3 = *(const f16x8*)(abase + 96);
    const int ncc = ncol >> 4;
    const int cic = lane & 15;
    const int rbase = (lane >> 4) << 2;
    for (int c0 = 0; c0 < ncc; ++c0) {
        const f16x8* wf = (const f16x8*)Wf + (size_t)c0 * 256 + lane;
        f32x4 acc = {0.f, 0.f, 0.f, 0.f};
        acc = __builtin_amdgcn_mfma_f32_16x16x32_f16(a0, wf[0],   acc, 0, 0, 0);
        acc = __builtin_amdgcn_mfma_f32_16x16x32_f16(a1, wf[64],  acc, 0, 0, 0);
        acc = __builtin_amdgcn_mfma_f32_16x16x32_f16(a2, wf[128], acc, 0, 0, 0);
        acc = __builtin_amdgcn_mfma_f32_16x16x32_f16(a3, wf[192], acc, 0, 0, 0);
        int colc = (c0 << 4) + cic;
        float bv = bias ? bias[colc] : 0.f;
#pragma unroll
        for (int r = 0; r < 4; ++r) {
            int row = row0 + rbase + r;
            if (row < n) {
                float v = acc[r] + bv;
                if (c_fp32) ((float*)C)[(size_t)row * ncol + colc] = v;
                else        ((__half*)C)[(size_t)row * ncol + colc] = __float2half(v);
            }
        }
    }
}

extern "C" void kernel_launch(void* const* d_in, const int* in_sizes, int n_in,
                              void* d_out, int out_size, void* d_ws, size_t ws_size,
                              hipStream_t stream) {
    const float* x  = (const float*)d_in[0];
    const void*  ei = d_in[1];
    const float* We = (const float*)d_in[2];
    const float* be = (const float*)d_in[3];
    const float* W1 = (const float*)d_in[4];
    const float* b1 = (const float*)d_in[5];
    const float* W2 = (const float*)d_in[6];
    const float* b2 = (const float*)d_in[7];
    const float* Wo = (const float*)d_in[8];
    const float* bo = (const float*)d_in[9];
    const int N = in_sizes[0] / 128;
    const int E = in_sizes[1] / 2;
    const int NC = in_sizes[9];  // NUM_CLASS = 64

    char* ws = (char*)d_ws;
    size_t off = 0;
    int*      flag = (int*)(ws + off);      off += 256;
    unsigned* bsum = (unsigned*)(ws + off); off += WS_ALIGN((size_t)SCAN_BLOCKS * 4);
    unsigned* ecnt = (unsigned*)(ws + off); off += WS_ALIGN((size_t)N * 4);
    float*    dinv = (float*)(ws + off);    off += WS_ALIGN((size_t)N * 4);
    int*      rowp = (int*)(ws + off);      off += WS_ALIGN((size_t)(N + 1) * 4);
    int*      fill = (int*)(ws + off);      off += WS_ALIGN((size_t)N * 4);
    int*      srcw = (int*)(ws + off);      off += WS_ALIGN((size_t)E * 4);
    int*      dstw = (int*)(ws + off);      off += WS_ALIGN((size_t)E * 4);
    int*      colw = (int*)(ws + off);      off += WS_ALIGN((size_t)E * 4);
    __half*   WeF  = (__half*)(ws + off);   off += WS_ALIGN((size_t)128 * 128 * 2);
    __half*   W1F  = (__half*)(ws + off);   off += WS_ALIGN((size_t)128 * 128 * 2);
    __half*   W2F  = (__half*)(ws + off);   off += WS_ALIGN((size_t)128 * 128 * 2);
    __half*   WoF  = (__half*)(ws + off);   off += WS_ALIGN((size_t)128 * 64 * 2);
    __half*   xH   = (__half*)(ws + off);   off += WS_ALIGN((size_t)N * 128 * 2);
    __half*   hA   = (__half*)(ws + off);   off += WS_ALIGN((size_t)N * 128 * 2);
    __half*   tH   = (__half*)(ws + off);   off += WS_ALIGN((size_t)N * 128 * 2);

    const int nb_n = (N + 255) / 256;
    const int nb_e = (E + 255) / 256;

    // edge prep + CSR build
    detect_i64_kernel<<<1, 256, 0, stream>>>((const unsigned*)ei, flag);
    convert_edges_kernel<<<nb_e, 256, 0, stream>>>(ei, flag, srcw, dstw, E);
    zero_u32_kernel<<<nb_n, 256, 0, stream>>>(ecnt, N);
    count_deg_kernel<<<nb_e, 256, 0, stream>>>(dstw, ecnt, E);
    scan_phaseA_kernel<<<SCAN_BLOCKS, SCAN_TPB, 0, stream>>>(ecnt, bsum, N);
    scan_phaseB_kernel<<<1, SCAN_BLOCKS, 0, stream>>>(bsum);
    scan_phaseC_kernel<<<SCAN_BLOCKS, SCAN_TPB, 0, stream>>>(ecnt, bsum, rowp, fill, dinv, N, E);
    edge_fill_part_kernel<<<nb_e * 8, 256, 0, stream>>>(srcw, dstw, fill, colw, E, N);

    // weight fragments + x fp16
    wfrag_kernel<<<8, 256, 0, stream>>>(We, WeF, 128);
    wfrag_kernel<<<8, 256, 0, stream>>>(W1, W1F, 128);
    wfrag_kernel<<<8, 256, 0, stream>>>(W2, W2F, 128);
    wfrag_kernel<<<4, 256, 0, stream>>>(Wo, WoF, NC);
    f32_to_f16_kernel<<<(N * 16 + 255) / 256, 256, 0, stream>>>(x, xH, N * 16);

    const int gemm_blocks = (N + 63) / 64;
    const int agg_blocks = (N + 7) / 8;
    dim3 blk(256);

    // encoder: h0 = x@We + be -> hA (fp16)
    gemm_mfma_kernel<<<gemm_blocks, blk, 0, stream>>>(xH, WeF, be, hA, N, 128, 0);
    // conv1: t1 = h0@W1 -> tH ; a1 = relu(Agg(t1)+b1) -> hA
    gemm_mfma_kernel<<<gemm_blocks, blk, 0, stream>>>(hA, W1F, nullptr, tH, N, 128, 0);
    agg_pull_kernel<<<agg_blocks, blk, 0, stream>>>(rowp, colw, dinv, tH, b1, hA, N);
    // conv2: t2 = a1@W2 -> tH ; a2 = relu(Agg(t2)+b2) -> hA
    gemm_mfma_kernel<<<gemm_blocks, blk, 0, stream>>>(hA, W2F, nullptr, tH, N, 128, 0);
    agg_pull_kernel<<<agg_blocks, blk, 0, stream>>>(rowp, colw, dinv, tH, b2, hA, N);
    // decoder: out = a2@Wo + bo -> d_out (fp32)
    gemm_mfma_kernel<<<gemm_blocks, blk, 0, stream>>>(hA, WoF, bo, d_out, N, NC, 1);
}